// Round 11
// baseline (1683.230 us; speedup 1.0000x reference)
//
#include <hip/hip_runtime.h>

// ---------------- problem constants ----------------
#define GRID_N   50
#define YDIM     2500      // 50*50
#define BATCH    16
#define NCTX     64
#define NTGT     128
#define BN       1024      // BATCH*NCTX
#define RDIM     128
#define ZDIM     64
#define HDIM     128
#define CCONV    32
#define NSTRIP   5         // 5 strips of 10 rows
#define STRIPROWS 10

typedef __attribute__((ext_vector_type(8))) short  s8v;   // 8 x bf16 (4 VGPR)
typedef __attribute__((ext_vector_type(4))) float  f4v;   // MFMA accum
typedef __attribute__((ext_vector_type(4))) unsigned int u4v;

__device__ __forceinline__ unsigned short f2bf(float f) {
    unsigned int u = __float_as_uint(f);
    u += 0x7FFFu + ((u >> 16) & 1u);
    return (unsigned short)(u >> 16);
}
__device__ __forceinline__ unsigned int cvtpk(float lo, float hi) {
    unsigned int r;
    asm("v_cvt_pk_bf16_f32 %0, %1, %2" : "=v"(r) : "v"(lo), "v"(hi));
    return r;
}

// ---------------- ws layout (bytes) ----------------
// w2p: 18432 @0 ; wdp: 1286144 @18432 ; part: 655360 @1304576 ;
// r_i: 524288 @1959936 ; zbuf: 4096 @2484224 ; h2d: 524288 @2488320 ;
// w1p: 2048 @3012608 ; treg: 1152 @3014656 ; cnt: 4160 @3015808
// -> total 3019968

// ---------------- k_conv smem layout (44928 B = 3 blocks/CU) ----------
// h1: 312 rows x 144B. row = pos>>1, byte-in-row = (pos&1)*64 + q*16.
// Affine: all tap offsets are compile-time immediates.
// y-plane + parity-dup aliased into h1 tail [40320, 44928) = tiles 35..38
// (written in phase B after planes die). main: pl[1+e] = y[e], e<736
// (pl[0]=0 pad); dup: pl[738+e] = y[e], e<734.
// After the final conv barrier the whole region is reused by the fused
// encoder tail (floats at [0, 6656); ticket flag int at 8192).
#define PLB   40320
#define SMEMB 44928
#define ROWB  144

// conv1 K-slot map (16x16x32, slots j>=4 of each q zero-weight):
//  q0:{t0,t1,t3,t4} q1:{t6,t7,t2,-} q2:{t5,-,t8,-} q3:{-,-,-,-}
// tap t = 3*ky+kx ; plane offset B(t) = 52*ky + kx - 1
// pair bases: Ba: q0=-1 q1=103 q2=53 q3=-1 ; Bb: q0=51 q1=1 q2=105 q3=-1

// =====================================================================
// merged pack: y<2 -> Wd frags ; y==2,x==0 -> w1p/w2p + treg + zero cnt
// =====================================================================
__global__ void k_pack(const float* __restrict__ w1, const float* __restrict__ b1,
                       const float* __restrict__ w2,
                       unsigned short* __restrict__ w2p, unsigned short* __restrict__ w1p,
                       float* __restrict__ tregG, int* __restrict__ cntb,
                       const float* __restrict__ Wmu, const float* __restrict__ Wsg,
                       unsigned short* __restrict__ wdp)
{
    int t = threadIdx.x;
    if (blockIdx.y == 2) {
        if (blockIdx.x != 0) return;
        // zero ticket counters (1024 per-sample + 16 per-batch)
        for (int e = t; e < 1040; e += 256) cntb[e] = 0;
        int l = t & 63, qq = t >> 6;
        int cout_lo = l & 15, cb = (l >> 4) & 3;
        for (int e = qq; e < 18; e += 4) {
            int tap = e >> 1, ntt = e & 1;
            int cout = ntt * 16 + cout_lo;
            unsigned int pk[4];
#pragma unroll
            for (int g = 0; g < 4; ++g) {
                int jj = 2 * g;
                int cinL = (jj < 4) ? (cb * 4 + jj) : (16 + cb * 4 + (jj - 4));
                unsigned int lo = f2bf(w2[(cout * 32 + cinL) * 9 + tap]);
                unsigned int hi = f2bf(w2[(cout * 32 + cinL + 1) * 9 + tap]);
                pk[g] = lo | (hi << 16);
            }
            uint4 o; o.x = pk[0]; o.y = pk[1]; o.z = pk[2]; o.w = pk[3];
            *(uint4*)&w2p[((tap * 2 + ntt) * 64 + l) * 8] = o;
        }
        if (t < 128) {
            int ct = t >> 6, lane = t & 63;
            int c = ct * 16 + (lane & 15), q2 = lane >> 4;
            const signed char ktab[16] = {0,1,3,4,  6,7,2,-1,  5,-1,8,-1,  -1,-1,-1,-1};
            unsigned short v8[8];
#pragma unroll
            for (int j = 0; j < 8; ++j) {
                v8[j] = 0;
                if (j < 4) {
                    int km = ktab[q2 * 4 + j];
                    if (km >= 0) v8[j] = f2bf(w1[(c * 2 + 0) * 9 + km]);
                }
            }
            uint4 o;
            o.x = (unsigned)v8[0] | ((unsigned)v8[1] << 16);
            o.y = (unsigned)v8[2] | ((unsigned)v8[3] << 16);
            o.z = (unsigned)v8[4] | ((unsigned)v8[5] << 16);
            o.w = (unsigned)v8[6] | ((unsigned)v8[7] << 16);
            *(uint4*)&w1p[(ct * 64 + lane) * 8] = o;
        }
        // x-channel region-sum table, regions ridx = rr*3+cc
        for (int e = t; e < 288; e += 256) {
            int ridx = e >> 5, c = e & 31;
            int rr = ridx / 3, cc = ridx % 3;
            float sum = 0.f;
            for (int ky = 0; ky < 3; ++ky)
                for (int kx = 0; kx < 3; ++kx) {
                    bool rok = !((rr == 0 && ky == 0) || (rr == 2 && ky == 2));
                    bool cok = !((cc == 0 && kx == 0) || (cc == 2 && kx == 2));
                    if (rok && cok) sum += w1[(c * 2 + 1) * 9 + ky * 3 + kx];
                }
            tregG[e] = sum;
        }
        return;
    }
    // ---- Wd pack ----
    int nt = blockIdx.x;          // 0..156
    int which = blockIdx.y;       // 0: mu, 1: sig
    const float* W = which ? Wsg : Wmu;
    unsigned short* outp = wdp + (size_t)which * (157 * 4 * 64 * 8);
    int l = t & 63, ks = t >> 6;
    int n = nt * 16 + (l & 15);
    int kbase = ks * 32 + ((l >> 4) & 3) * 8;
    unsigned int pk[4];
#pragma unroll
    for (int g = 0; g < 4; ++g) {
        float f0 = (n < 2500) ? W[(kbase + 2 * g) * 2500 + n] : 0.f;
        float f1 = (n < 2500) ? W[(kbase + 2 * g + 1) * 2500 + n] : 0.f;
        pk[g] = (unsigned int)f2bf(f0) | ((unsigned int)f2bf(f1) << 16);
    }
    uint4 o; o.x = pk[0]; o.y = pk[1]; o.z = pk[2]; o.w = pk[3];
    *(uint4*)&outp[((nt * 4 + ks) * 64 + l) * 8] = o;
}

// =====================================================================
// conv1 + conv2 (unchanged body) + fused encoder/mu-sigma tails via
// atomic tickets: 5th strip-block of a sample runs the per-sample MLP;
// 64th sample-finisher of a batch runs the mu/sigma/z stage.
// =====================================================================
__global__ __launch_bounds__(512, 6) void k_conv(
    const float* __restrict__ xc, const float* __restrict__ yc,
    const unsigned short* __restrict__ w1p, const unsigned short* __restrict__ w2p,
    const float* __restrict__ b1, const float* __restrict__ b2,
    const float* __restrict__ tregG, float* __restrict__ part,
    const float* __restrict__ We1, const float* __restrict__ be1,
    const float* __restrict__ We2, const float* __restrict__ be2,
    const float* __restrict__ Wh,  const float* __restrict__ bh,
    const float* __restrict__ Wmu, const float* __restrict__ bmu,
    const float* __restrict__ Wsig,const float* __restrict__ bsig,
    const float* __restrict__ eps, float* __restrict__ r_i,
    float* __restrict__ zbuf, float* __restrict__ outg,
    int* __restrict__ cnt, int* __restrict__ cnt2)
{
    __shared__ __align__(16) char smem[SMEMB];
    unsigned short* pl = (unsigned short*)(smem + PLB);
    float* redbuf = (float*)smem;   // alias, used after post-conv2 barrier

    const int t = threadIdx.x, lane = t & 63, w = t >> 6;
    const int l15 = lane & 15, q = lane >> 4;
    const int par = lane & 1;
    const int blk = blockIdx.x, s = blk / NSTRIP, strip = blk - s * NSTRIP;
    const int r0 = strip * STRIPROWS;

    const float xv = xc[s];
    const float b2v0 = b2[l15], b2v1 = b2[16 + l15];
    const float4 bv0 = *(const float4*)&b1[q * 4];
    const float4 bv1 = *(const float4*)&b1[16 + q * 4];
    const f4v bC0 = {bv0.x, bv0.y, bv0.z, bv0.w};   // conv1 C-in (rows=channels)
    const f4v bC1 = {bv1.x, bv1.y, bv1.z, bv1.w};
    const f4v cb0 = {b2v0, b2v0, b2v0, b2v0};       // conv2 C-in (cols=channels)
    const f4v cb1 = {b2v1, b2v1, b2v1, b2v1};

    // fill y-plane (+ parity dup). ry = e/52 via magic (valid e<736)
    if (t == 0) pl[0] = 0;
    for (int e = t; e < 736; e += 512) {
        unsigned ry = ((unsigned)(e * 1261)) >> 16;
        int ycol = e - (int)ry * 52;
        int gy = r0 - 2 + (int)ry, gc = ycol - 1;
        unsigned short yb = 0;
        if (((unsigned)gy < 50u) && ((unsigned)gc < 50u))
            yb = f2bf(yc[s * YDIM + gy * 50 + gc]);
        pl[1 + e] = yb;
        if (e < 734) pl[738 + e] = yb;
    }

    // conv1 weight fragments (L2-resident)
    s8v w1f[2];
#pragma unroll
    for (int ct = 0; ct < 2; ++ct)
        w1f[ct] = *(const s8v*)&w1p[(ct * 64 + lane) * 8];

    // per-lane gather bases (byte offsets into smem; +32*mt per tile)
    int Ba = (q == 0) ? -1 : (q == 1) ? 103 : (q == 2) ? 53 : -1;
    int Bb = (q == 0) ? 51 : (q == 1) ? 1 : (q == 2) ? 105 : -1;
    auto mkoff = [&](int B) {
        int pr = (B + 1 + par) & 1;
        return PLB + (pr ? 2 * (738 + B) : 2 * (1 + B)) + 2 * l15;
    };
    const int go0 = mkoff(Ba), go1 = mkoff(Bb);
    // per-lane write base (byte offset; +1152*mt per tile)
    const int wo = (l15 >> 1) * ROWB + (l15 & 1) * 64 + q * 16;

    __syncthreads();

    // ---------------- conv1: M=624 (12x52 pos space), N=32, K=9 y-taps ----
    auto do_tile = [&](int mt) -> uint4 {
        int mo = mt * 32;
        unsigned g0 = *(const unsigned*)(smem + go0 + mo);
        unsigned g1 = *(const unsigned*)(smem + go1 + mo);
        u4v gg = {g0, g1, 0u, 0u};
        s8v af = __builtin_bit_cast(s8v, gg);
        f4v c0 = __builtin_amdgcn_mfma_f32_16x16x32_bf16(w1f[0], af, bC0, 0, 0, 0);
        f4v c1 = __builtin_amdgcn_mfma_f32_16x16x32_bf16(w1f[1], af, bC1, 0, 0, 0);
        int m = mt * 16 + l15;
        unsigned mr = ((unsigned)(m * 1261)) >> 16;     // m/52
        int mc = m - (int)mr * 52;
        int gy = r0 - 1 + (int)mr;
        int gc = mc - 1;
        bool valid = ((unsigned)gc < 50u) && ((unsigned)gy < 50u);
        int rr = (gy == 0) ? 0 : ((gy == 49) ? 2 : 1);
        int cc = (gc == 0) ? 0 : ((gc == 49) ? 2 : 1);
        int ridx = rr * 3 + cc;
        float4 tg0 = *(const float4*)&tregG[ridx * 32 + q * 4];
        float4 tg1 = *(const float4*)&tregG[ridx * 32 + 16 + q * 4];
        c0[0] = fmaf(xv, tg0.x, c0[0]);
        c0[1] = fmaf(xv, tg0.y, c0[1]);
        c0[2] = fmaf(xv, tg0.z, c0[2]);
        c0[3] = fmaf(xv, tg0.w, c0[3]);
        c1[0] = fmaf(xv, tg1.x, c1[0]);
        c1[1] = fmaf(xv, tg1.y, c1[1]);
        c1[2] = fmaf(xv, tg1.z, c1[2]);
        c1[3] = fmaf(xv, tg1.w, c1[3]);
        unsigned p0 = cvtpk(fmaxf(c0[0], 0.f), fmaxf(c0[1], 0.f));
        unsigned p1 = cvtpk(fmaxf(c0[2], 0.f), fmaxf(c0[3], 0.f));
        unsigned p2 = cvtpk(fmaxf(c1[0], 0.f), fmaxf(c1[1], 0.f));
        unsigned p3 = cvtpk(fmaxf(c1[2], 0.f), fmaxf(c1[3], 0.f));
        if (!valid) { p0 = 0u; p1 = 0u; p2 = 0u; p3 = 0u; }
        return make_uint4(p0, p1, p2, p3);
    };
    auto wr_tile = [&](int mt, uint4 v) {
        *(uint4*)(smem + wo + mt * 1152) = v;
    };

    // phase A: tiles 0..34 (write region disjoint from planes)
#pragma unroll 5
    for (int it = 0; it < 5; ++it) {
        int mt = w + it * 8;
        if (mt <= 34) {
            uint4 v = do_tile(mt);
            wr_tile(mt, v);
        }
    }
    // phase B: tiles 35..38 held by waves 0..3 (bytes overlap planes)
    {
        bool hold = (w < 4);
        uint4 hA = make_uint4(0u, 0u, 0u, 0u);
        int mt0 = 35 + w;
        if (hold) hA = do_tile(mt0);
        __syncthreads();                 // planes dead from here
        if (hold) wr_tile(mt0, hA);
    }
    __syncthreads();

    // ---------------- conv2: M=512(pad), N=32, K=288, tap-outer ----------------
    f4v acc[4][2];
#pragma unroll
    for (int i = 0; i < 4; ++i) { acc[i][0] = cb0; acc[i][1] = cb1; }
    int bE[4], bO[4];
#pragma unroll
    for (int tt = 0; tt < 4; ++tt) {
        int m2 = (w * 4 + tt) * 16 + l15;
        unsigned orr = ((unsigned)(m2 * 1311)) >> 16;   // m2/50
        int pu = (m2 + 2 * (int)orr) >> 1;
        pu = (pu > 258) ? 258 : pu;
        bE[tt] = pu * ROWB + (par << 6) + (q << 4);
        bO[tt] = bE[tt] + (par ? 80 : 64);
    }
    __builtin_amdgcn_s_setprio(1);
#pragma unroll
    for (int tp = 0; tp < 9; ++tp) {
        const int ky = tp / 3, kx = tp % 3;
        const int off = 3744 * ky + (kx == 2 ? ROWB : 0);
        s8v b0 = *(const s8v*)&w2p[((tp * 2 + 0) * 64 + lane) * 8];
        s8v b1f = *(const s8v*)&w2p[((tp * 2 + 1) * 64 + lane) * 8];
#pragma unroll
        for (int tt = 0; tt < 4; ++tt) {
            s8v a = *(const s8v*)(smem + (kx == 1 ? bO[tt] : bE[tt]) + off);
            acc[tt][0] = __builtin_amdgcn_mfma_f32_16x16x32_bf16(a, b0, acc[tt][0], 0, 0, 0);
            acc[tt][1] = __builtin_amdgcn_mfma_f32_16x16x32_bf16(a, b1f, acc[tt][1], 0, 0, 0);
        }
    }
    __builtin_amdgcn_s_setprio(0);

    // fused relu + spatial partial sum
    float ps0 = 0.f, ps1 = 0.f;
#pragma unroll
    for (int tt = 0; tt < 4; ++tt) {
        int tile = w * 4 + tt;             // wave-uniform
        if (tile != 31) {
#pragma unroll
            for (int r = 0; r < 4; ++r) {
                ps0 += fmaxf(acc[tt][0][r], 0.f);
                ps1 += fmaxf(acc[tt][1][r], 0.f);
            }
        } else {
            int mbase = tile * 16 + q * 4;
#pragma unroll
            for (int r = 0; r < 4; ++r) {
                if (mbase + r < 500) {
                    ps0 += fmaxf(acc[tt][0][r], 0.f);
                    ps1 += fmaxf(acc[tt][1][r], 0.f);
                }
            }
        }
    }
    ps0 += __shfl_xor(ps0, 16); ps0 += __shfl_xor(ps0, 32);
    ps1 += __shfl_xor(ps1, 16); ps1 += __shfl_xor(ps1, 32);
    __syncthreads();                       // conv2 reads done -> redbuf alias safe
    if (lane < 16) {
        redbuf[w * 32 + l15] = ps0;
        redbuf[w * 32 + 16 + l15] = ps1;
    }
    __syncthreads();
    if (t < 32) {
        float v = 0.f;
#pragma unroll
        for (int k = 0; k < 8; ++k) v += redbuf[k * 32 + t];
        part[(s * NSTRIP + strip) * 32 + t] = v;
    }

    // ================= fused encoder tail (ticket: last of 5 strips) =====
    __threadfence();
    __syncthreads();
    int* flagp = (int*)(smem + 8192);
    if (t == 0) {
        int old = atomicAdd(&cnt[s], 1);
        *flagp = (old == 4) ? 1 : 0;
    }
    __syncthreads();
    if (!*flagp) return;
    __threadfence();

    float* F   = (float*)smem;         // feat[33]
    float* hB  = (float*)smem + 64;    // h[128]
    float* rrB = (float*)smem + 256;   // r[128]
    float* hrB = (float*)smem + 448;   // hr[128]
    float* tmp = (float*)smem + 640;   // tmp[8][128]

    if (t < 33) {
        float v;
        if (t < 32) {
            v = 0.f;
#pragma unroll
            for (int st = 0; st < NSTRIP; ++st) v += part[(s * NSTRIP + st) * 32 + t];
            v *= (1.f / 2500.f);
        } else v = xv;
        F[t] = v;
    }
    __syncthreads();
    const int j = t & 127, g = t >> 7;    // g in 0..3
    {
        int k0 = g * 8, k1 = (g == 3) ? 33 : (g * 8 + 8);
        float a = (g == 0) ? be1[j] : 0.f;
        for (int k = k0; k < k1; ++k) a = fmaf(F[k], We1[k * 128 + j], a);
        tmp[g * 128 + j] = a;
    }
    __syncthreads();
    if (g == 0) hB[j] = fmaxf(tmp[j] + tmp[128 + j] + tmp[256 + j] + tmp[384 + j], 0.f);
    __syncthreads();
    {
        float a = (g == 0) ? be2[j] : 0.f;
#pragma unroll 8
        for (int k = g * 32; k < g * 32 + 32; ++k) a = fmaf(hB[k], We2[k * 128 + j], a);
        tmp[g * 128 + j] = a;
    }
    __syncthreads();
    if (g == 0) r_i[s * 128 + j] = tmp[j] + tmp[128 + j] + tmp[256 + j] + tmp[384 + j];

    // ================= fused mu/sigma tail (ticket: last of 64 samples) ==
    __threadfence();
    __syncthreads();
    const int b = s >> 6;
    if (t == 0) {
        int old = atomicAdd(&cnt2[b], 1);
        *flagp = (old == 63) ? 1 : 0;
    }
    __syncthreads();
    if (!*flagp) return;
    __threadfence();

    {
        float a = 0.f;
#pragma unroll 4
        for (int i = g * 16; i < g * 16 + 16; ++i)
            a += r_i[(b * 64 + i) * 128 + j];
        tmp[g * 128 + j] = a;
    }
    __syncthreads();
    if (g == 0) rrB[j] = (tmp[j] + tmp[128 + j] + tmp[256 + j] + tmp[384 + j]) * (1.f / 64.f);
    __syncthreads();
    {
        float a = (g == 0) ? bh[j] : 0.f;
#pragma unroll 8
        for (int k = g * 32; k < g * 32 + 32; ++k) a = fmaf(rrB[k], Wh[k * 128 + j], a);
        tmp[g * 128 + j] = a;
    }
    __syncthreads();
    if (g == 0) hrB[j] = fmaxf(tmp[j] + tmp[128 + j] + tmp[256 + j] + tmp[384 + j], 0.f);
    __syncthreads();
    {
        int j2 = t & 63, g2 = t >> 6;      // 0..7
        const float* W = (g2 >= 4) ? Wsig : Wmu;
        int kb = (g2 & 3) * 32;
        float a = 0.f;
        if (g2 == 0) a = bmu[j2];
        if (g2 == 4) a = bsig[j2];
#pragma unroll 8
        for (int k = kb; k < kb + 32; ++k) a = fmaf(hrB[k], W[k * 64 + j2], a);
        tmp[g2 * 128 + j2] = a;
    }
    __syncthreads();
    if (t < 64) {
        float m  = tmp[t] + tmp[128 + t] + tmp[256 + t] + tmp[384 + t];
        float sg = tmp[512 + t] + tmp[640 + t] + tmp[768 + t] + tmp[896 + t];
        float sig = 0.1f + 0.9f / (1.f + expf(-sg));
        outg[10240000 + b * 64 + t] = m;      // mu_c
        outg[10241024 + b * 64 + t] = sig;    // sigma_c
        zbuf[b * 64 + t] = m + sig * eps[b * 64 + t];
    }
}

// =====================================================================
// decoder hidden: 512 blocks x 256 thr, 4 rows/block (2 per half-group)
// =====================================================================
__global__ __launch_bounds__(256) void k_dec1(
    const float* __restrict__ xt, const float* __restrict__ zbuf,
    const float* __restrict__ Wd1, const float* __restrict__ bd1,
    const float* __restrict__ Wd2, const float* __restrict__ bd2,
    unsigned short* __restrict__ h2d)
{
    __shared__ float zsh[64];
    __shared__ float vsh[2][128];
    __shared__ float h1sh[4][128];
    int t = threadIdx.x;
    int j = t & 127, g = t >> 7;
    int r0 = blockIdx.x * 4;
    int b = r0 >> 7;
    if (t < 64) zsh[t] = zbuf[b * 64 + t];
    __syncthreads();
    float v = (g == 0) ? bd1[j] : 0.f;
#pragma unroll 8
    for (int k = g * 32; k < g * 32 + 32; ++k)
        v = fmaf(zsh[k], Wd1[(1 + k) * 128 + j], v);
    vsh[g][j] = v;
    __syncthreads();
    float vv = vsh[0][j] + vsh[1][j];
    float w0 = Wd1[j];
    int ra = r0 + g * 2;
    float x0 = xt[ra], x1 = xt[ra + 1];
    h1sh[g * 2][j]     = fmaxf(fmaf(x0, w0, vv), 0.f);
    h1sh[g * 2 + 1][j] = fmaxf(fmaf(x1, w0, vv), 0.f);
    __syncthreads();
    float bd2j = bd2[j];
    float a0 = bd2j, a1 = bd2j;
#pragma unroll 8
    for (int k = 0; k < 128; ++k) {
        float wv = Wd2[k * 128 + j];
        a0 = fmaf(h1sh[g * 2][k], wv, a0);
        a1 = fmaf(h1sh[g * 2 + 1][k], wv, a1);
    }
    h2d[(size_t)ra * 128 + j]       = f2bf(fmaxf(a0, 0.f));
    h2d[(size_t)(ra + 1) * 128 + j] = f2bf(fmaxf(a1, 0.f));
}

// =====================================================================
// big decoder GEMM: [2048,128] @ [128,2500], BOTH heads per block,
// bias preloaded into accumulator C-in
// =====================================================================
__global__ __launch_bounds__(256) void k_gemm(
    const unsigned short* __restrict__ h2d, const unsigned short* __restrict__ wdp,
    const float* __restrict__ bdmu, const float* __restrict__ bdsg,
    float* __restrict__ out)
{
    __shared__ __align__(16) unsigned short Al[64 * 128];
    int t = threadIdx.x, lane = t & 63, w = t >> 6;
    int m0 = blockIdx.x * 64;
#pragma unroll
    for (int i = 0; i < 4; ++i) {
        int g = t + i * 256;
        int row = g >> 4, bk = g & 15;
        uint4 v = *(const uint4*)&h2d[(size_t)(m0 + row) * 128 + bk * 8];
        *(uint4*)&Al[row * 128 + ((bk ^ (row & 7)) << 3)] = v;
    }
    __syncthreads();
    int nt = blockIdx.y * 4 + w;
    if (nt < 157) {
        int lcol = lane & 15, lq = lane >> 4;
        int col = nt * 16 + lcol;
        bool cok = (col < 2500);
#pragma unroll
        for (int which = 0; which < 2; ++which) {
            const unsigned short* wp = wdp + (size_t)which * (157 * 4 * 64 * 8);
            s8v bfr[4];
#pragma unroll
            for (int ks = 0; ks < 4; ++ks)
                bfr[ks] = *(const s8v*)&wp[((nt * 4 + ks) * 64 + lane) * 8];
            float bv = cok ? (which ? bdsg[col] : bdmu[col]) : 0.f;
            f4v acc[4];
            {
                f4v bcast = {bv, bv, bv, bv};
#pragma unroll
                for (int mt = 0; mt < 4; ++mt) acc[mt] = bcast;
            }
#pragma unroll
            for (int mt = 0; mt < 4; ++mt) {
                int mrow = mt * 16 + lcol;
#pragma unroll
                for (int ks = 0; ks < 4; ++ks) {
                    int bk = ks * 4 + lq;
                    s8v a = *(const s8v*)&Al[mrow * 128 + ((bk ^ (mrow & 7)) << 3)];
                    acc[mt] = __builtin_amdgcn_mfma_f32_16x16x32_bf16(a, bfr[ks], acc[mt], 0, 0, 0);
                }
            }
            if (cok) {
                size_t zoff = (size_t)which * 5120000;
#pragma unroll
                for (int mt = 0; mt < 4; ++mt)
#pragma unroll
                    for (int r = 0; r < 4; ++r) {
                        int row = m0 + mt * 16 + lq * 4 + r;
                        float vv = acc[mt][r];
                        if (which) {
                            float sp = fmaxf(vv, 0.f) + log1pf(expf(-fabsf(vv)));
                            vv = 0.1f + 0.9f * sp;
                        }
                        out[zoff + (size_t)row * 2500 + col] = vv;
                    }
            }
        }
    }
}

// =====================================================================
extern "C" void kernel_launch(void* const* d_in, const int* in_sizes, int n_in,
                              void* d_out, int out_size, void* d_ws, size_t ws_size,
                              hipStream_t stream)
{
    const float* xc   = (const float*)d_in[0];
    const float* yc   = (const float*)d_in[1];
    const float* xt   = (const float*)d_in[2];
    const float* eps  = (const float*)d_in[3];
    const float* w1   = (const float*)d_in[4];
    const float* b1   = (const float*)d_in[5];
    const float* w2   = (const float*)d_in[6];
    const float* b2   = (const float*)d_in[7];
    const float* We1  = (const float*)d_in[8];
    const float* be1  = (const float*)d_in[9];
    const float* We2  = (const float*)d_in[10];
    const float* be2  = (const float*)d_in[11];
    const float* Wh   = (const float*)d_in[12];
    const float* bh   = (const float*)d_in[13];
    const float* Wmu  = (const float*)d_in[14];
    const float* bmu  = (const float*)d_in[15];
    const float* Wsig = (const float*)d_in[16];
    const float* bsig = (const float*)d_in[17];
    const float* Wd1  = (const float*)d_in[18];
    const float* bd1  = (const float*)d_in[19];
    const float* Wd2  = (const float*)d_in[20];
    const float* bd2  = (const float*)d_in[21];
    const float* Wdmu = (const float*)d_in[22];
    const float* bdmu = (const float*)d_in[23];
    const float* Wdsg = (const float*)d_in[24];
    const float* bdsg = (const float*)d_in[25];

    float* out = (float*)d_out;
    char* wsb  = (char*)d_ws;
    unsigned short* w2p = (unsigned short*)(wsb + 0);
    unsigned short* wdp = (unsigned short*)(wsb + 18432);
    float* part = (float*)(wsb + 1304576);
    float* r_i  = (float*)(wsb + 1959936);
    float* zbuf = (float*)(wsb + 2484224);
    unsigned short* h2d = (unsigned short*)(wsb + 2488320);
    unsigned short* w1p = (unsigned short*)(wsb + 3012608);
    float* treg = (float*)(wsb + 3014656);
    int*   cntb = (int*)(wsb + 3015808);      // cnt[1024] + cnt2[16]

    hipLaunchKernelGGL(k_pack, dim3(157, 3), dim3(256), 0, stream,
                       w1, b1, w2, w2p, w1p, treg, cntb, Wdmu, Wdsg, wdp);
    hipLaunchKernelGGL(k_conv, dim3(BN * NSTRIP), dim3(512), 0, stream,
                       xc, yc, w1p, w2p, b1, b2, treg, part,
                       We1, be1, We2, be2, Wh, bh, Wmu, bmu, Wsig, bsig,
                       eps, r_i, zbuf, out, cntb, cntb + 1024);
    hipLaunchKernelGGL(k_dec1, dim3(512), dim3(256), 0, stream,
                       xt, zbuf, Wd1, bd1, Wd2, bd2, h2d);
    hipLaunchKernelGGL(k_gemm, dim3(32, 40), dim3(256), 0, stream,
                       h2d, wdp, bdmu, bdsg, out);
}

// Round 12
// 117.368 us; speedup vs baseline: 14.3415x; 14.3415x over previous
//
#include <hip/hip_runtime.h>

// ---------------- problem constants ----------------
#define GRID_N   50
#define YDIM     2500      // 50*50
#define BATCH    16
#define NCTX     64
#define NTGT     128
#define BN       1024      // BATCH*NCTX
#define RDIM     128
#define ZDIM     64
#define HDIM     128
#define CCONV    32
#define NSTRIP   5         // 5 strips of 10 rows
#define STRIPROWS 10

typedef __attribute__((ext_vector_type(8))) short  s8v;   // 8 x bf16 (4 VGPR)
typedef __attribute__((ext_vector_type(4))) float  f4v;   // MFMA accum
typedef __attribute__((ext_vector_type(4))) unsigned int u4v;

__device__ __forceinline__ unsigned short f2bf(float f) {
    unsigned int u = __float_as_uint(f);
    u += 0x7FFFu + ((u >> 16) & 1u);
    return (unsigned short)(u >> 16);
}
__device__ __forceinline__ unsigned int cvtpk(float lo, float hi) {
    unsigned int r;
    asm("v_cvt_pk_bf16_f32 %0, %1, %2" : "=v"(r) : "v"(lo), "v"(hi));
    return r;
}

// ---------------- ws layout (bytes) ----------------
// w2p: 18432 @0 ; wdp: 1286144 @18432 ; part: 655360 @1304576 ;
// r_i: 524288 @1959936 ; zbuf: 4096 @2484224 ; h2d: 524288 @2488320 ;
// w1p: 2048 @3012608 ; treg: 1152 @3014656  -> total 3015808

// ---------------- k_conv smem layout (44928 B = 3 blocks/CU) ----------
// h1: 312 rows x 144B. row = pos>>1, byte-in-row = (pos&1)*64 + q*16.
// Affine: all tap offsets are compile-time immediates.
// y-plane + parity-dup aliased into h1 tail [40320, 44928) = tiles 35..38
// (written in phase B after planes die). main: pl[1+e] = y[e], e<736
// (pl[0]=0 pad); dup: pl[738+e] = y[e], e<734.
#define PLB   40320
#define SMEMB 44928
#define ROWB  144

// conv1 K-slot map (16x16x32, slots j>=4 of each q zero-weight):
//  q0:{t0,t1,t3,t4} q1:{t6,t7,t2,-} q2:{t5,-,t8,-} q3:{-,-,-,-}
// tap t = 3*ky+kx ; plane offset B(t) = 52*ky + kx - 1
// pair bases: Ba: q0=-1 q1=103 q2=53 q3=-1 ; Bb: q0=51 q1=1 q2=105 q3=-1

// =====================================================================
// merged pack: y<2 -> Wd frags ; y==2,x==0 -> w1p/w2p + region table treg
// =====================================================================
__global__ void k_pack(const float* __restrict__ w1, const float* __restrict__ b1,
                       const float* __restrict__ w2,
                       unsigned short* __restrict__ w2p, unsigned short* __restrict__ w1p,
                       float* __restrict__ tregG,
                       const float* __restrict__ Wmu, const float* __restrict__ Wsg,
                       unsigned short* __restrict__ wdp)
{
    int t = threadIdx.x;
    if (blockIdx.y == 2) {
        if (blockIdx.x != 0) return;
        int l = t & 63, qq = t >> 6;
        int cout_lo = l & 15, cb = (l >> 4) & 3;
        for (int e = qq; e < 18; e += 4) {
            int tap = e >> 1, ntt = e & 1;
            int cout = ntt * 16 + cout_lo;
            unsigned int pk[4];
#pragma unroll
            for (int g = 0; g < 4; ++g) {
                int jj = 2 * g;
                int cinL = (jj < 4) ? (cb * 4 + jj) : (16 + cb * 4 + (jj - 4));
                unsigned int lo = f2bf(w2[(cout * 32 + cinL) * 9 + tap]);
                unsigned int hi = f2bf(w2[(cout * 32 + cinL + 1) * 9 + tap]);
                pk[g] = lo | (hi << 16);
            }
            uint4 o; o.x = pk[0]; o.y = pk[1]; o.z = pk[2]; o.w = pk[3];
            *(uint4*)&w2p[((tap * 2 + ntt) * 64 + l) * 8] = o;
        }
        if (t < 128) {
            int ct = t >> 6, lane = t & 63;
            int c = ct * 16 + (lane & 15), q2 = lane >> 4;
            const signed char ktab[16] = {0,1,3,4,  6,7,2,-1,  5,-1,8,-1,  -1,-1,-1,-1};
            unsigned short v8[8];
#pragma unroll
            for (int j = 0; j < 8; ++j) {
                v8[j] = 0;
                if (j < 4) {
                    int km = ktab[q2 * 4 + j];
                    if (km >= 0) v8[j] = f2bf(w1[(c * 2 + 0) * 9 + km]);
                }
            }
            uint4 o;
            o.x = (unsigned)v8[0] | ((unsigned)v8[1] << 16);
            o.y = (unsigned)v8[2] | ((unsigned)v8[3] << 16);
            o.z = (unsigned)v8[4] | ((unsigned)v8[5] << 16);
            o.w = (unsigned)v8[6] | ((unsigned)v8[7] << 16);
            *(uint4*)&w1p[(ct * 64 + lane) * 8] = o;
        }
        // x-channel region-sum table, regions ridx = rr*3+cc
        for (int e = t; e < 288; e += 256) {
            int ridx = e >> 5, c = e & 31;
            int rr = ridx / 3, cc = ridx % 3;
            float sum = 0.f;
            for (int ky = 0; ky < 3; ++ky)
                for (int kx = 0; kx < 3; ++kx) {
                    bool rok = !((rr == 0 && ky == 0) || (rr == 2 && ky == 2));
                    bool cok = !((cc == 0 && kx == 0) || (cc == 2 && kx == 2));
                    if (rok && cok) sum += w1[(c * 2 + 1) * 9 + ky * 3 + kx];
                }
            tregG[e] = sum;
        }
        return;
    }
    // ---- Wd pack ----
    int nt = blockIdx.x;          // 0..156
    int which = blockIdx.y;       // 0: mu, 1: sig
    const float* W = which ? Wsg : Wmu;
    unsigned short* outp = wdp + (size_t)which * (157 * 4 * 64 * 8);
    int l = t & 63, ks = t >> 6;
    int n = nt * 16 + (l & 15);
    int kbase = ks * 32 + ((l >> 4) & 3) * 8;
    unsigned int pk[4];
#pragma unroll
    for (int g = 0; g < 4; ++g) {
        float f0 = (n < 2500) ? W[(kbase + 2 * g) * 2500 + n] : 0.f;
        float f1 = (n < 2500) ? W[(kbase + 2 * g + 1) * 2500 + n] : 0.f;
        pk[g] = (unsigned int)f2bf(f0) | ((unsigned int)f2bf(f1) << 16);
    }
    uint4 o; o.x = pk[0]; o.y = pk[1]; o.z = pk[2]; o.w = pk[3];
    *(uint4*)&outp[((nt * 4 + ks) * 64 + l) * 8] = o;
}

// =====================================================================
// conv1 + conv2, 512 threads (8 waves), 3 blocks/CU
// =====================================================================
__global__ __launch_bounds__(512, 6) void k_conv(
    const float* __restrict__ xc, const float* __restrict__ yc,
    const unsigned short* __restrict__ w1p, const unsigned short* __restrict__ w2p,
    const float* __restrict__ b1, const float* __restrict__ b2,
    const float* __restrict__ tregG, float* __restrict__ part)
{
    __shared__ __align__(16) char smem[SMEMB];
    unsigned short* pl = (unsigned short*)(smem + PLB);
    float* redbuf = (float*)smem;   // alias, used after post-conv2 barrier

    const int t = threadIdx.x, lane = t & 63, w = t >> 6;
    const int l15 = lane & 15, q = lane >> 4;
    const int par = lane & 1;
    const int blk = blockIdx.x, s = blk / NSTRIP, strip = blk - s * NSTRIP;
    const int r0 = strip * STRIPROWS;

    const float xv = xc[s];
    const float b2v0 = b2[l15], b2v1 = b2[16 + l15];
    const float4 bv0 = *(const float4*)&b1[q * 4];
    const float4 bv1 = *(const float4*)&b1[16 + q * 4];
    const f4v bC0 = {bv0.x, bv0.y, bv0.z, bv0.w};   // conv1 C-in (rows=channels)
    const f4v bC1 = {bv1.x, bv1.y, bv1.z, bv1.w};
    const f4v cb0 = {b2v0, b2v0, b2v0, b2v0};       // conv2 C-in (cols=channels)
    const f4v cb1 = {b2v1, b2v1, b2v1, b2v1};

    // fill y-plane (+ parity dup). ry = e/52 via magic (valid e<736)
    if (t == 0) pl[0] = 0;
    for (int e = t; e < 736; e += 512) {
        unsigned ry = ((unsigned)(e * 1261)) >> 16;
        int ycol = e - (int)ry * 52;
        int gy = r0 - 2 + (int)ry, gc = ycol - 1;
        unsigned short yb = 0;
        if (((unsigned)gy < 50u) && ((unsigned)gc < 50u))
            yb = f2bf(yc[s * YDIM + gy * 50 + gc]);
        pl[1 + e] = yb;
        if (e < 734) pl[738 + e] = yb;
    }

    // conv1 weight fragments (L2-resident)
    s8v w1f[2];
#pragma unroll
    for (int ct = 0; ct < 2; ++ct)
        w1f[ct] = *(const s8v*)&w1p[(ct * 64 + lane) * 8];

    // per-lane gather bases (byte offsets into smem; +32*mt per tile)
    int Ba = (q == 0) ? -1 : (q == 1) ? 103 : (q == 2) ? 53 : -1;
    int Bb = (q == 0) ? 51 : (q == 1) ? 1 : (q == 2) ? 105 : -1;
    auto mkoff = [&](int B) {
        int pr = (B + 1 + par) & 1;
        return PLB + (pr ? 2 * (738 + B) : 2 * (1 + B)) + 2 * l15;
    };
    const int go0 = mkoff(Ba), go1 = mkoff(Bb);
    // per-lane write base (byte offset; +1152*mt per tile)
    // slot = 4*(m&1) + q  ->  byte = row*144 + (m&1)*64 + q*16
    const int wo = (l15 >> 1) * ROWB + (l15 & 1) * 64 + q * 16;

    __syncthreads();

    // ---------------- conv1: M=624 (12x52 pos space), N=32, K=9 y-taps ----
    auto do_tile = [&](int mt) -> uint4 {
        int mo = mt * 32;
        unsigned g0 = *(const unsigned*)(smem + go0 + mo);
        unsigned g1 = *(const unsigned*)(smem + go1 + mo);
        u4v gg = {g0, g1, 0u, 0u};
        s8v af = __builtin_bit_cast(s8v, gg);
        f4v c0 = __builtin_amdgcn_mfma_f32_16x16x32_bf16(w1f[0], af, bC0, 0, 0, 0);
        f4v c1 = __builtin_amdgcn_mfma_f32_16x16x32_bf16(w1f[1], af, bC1, 0, 0, 0);
        int m = mt * 16 + l15;
        unsigned mr = ((unsigned)(m * 1261)) >> 16;     // m/52
        int mc = m - (int)mr * 52;
        int gy = r0 - 1 + (int)mr;
        int gc = mc - 1;
        bool valid = ((unsigned)gc < 50u) && ((unsigned)gy < 50u);
        int rr = (gy == 0) ? 0 : ((gy == 49) ? 2 : 1);
        int cc = (gc == 0) ? 0 : ((gc == 49) ? 2 : 1);
        int ridx = rr * 3 + cc;
        float4 tg0 = *(const float4*)&tregG[ridx * 32 + q * 4];
        float4 tg1 = *(const float4*)&tregG[ridx * 32 + 16 + q * 4];
        c0[0] = fmaf(xv, tg0.x, c0[0]);
        c0[1] = fmaf(xv, tg0.y, c0[1]);
        c0[2] = fmaf(xv, tg0.z, c0[2]);
        c0[3] = fmaf(xv, tg0.w, c0[3]);
        c1[0] = fmaf(xv, tg1.x, c1[0]);
        c1[1] = fmaf(xv, tg1.y, c1[1]);
        c1[2] = fmaf(xv, tg1.z, c1[2]);
        c1[3] = fmaf(xv, tg1.w, c1[3]);
        unsigned p0 = cvtpk(fmaxf(c0[0], 0.f), fmaxf(c0[1], 0.f));
        unsigned p1 = cvtpk(fmaxf(c0[2], 0.f), fmaxf(c0[3], 0.f));
        unsigned p2 = cvtpk(fmaxf(c1[0], 0.f), fmaxf(c1[1], 0.f));
        unsigned p3 = cvtpk(fmaxf(c1[2], 0.f), fmaxf(c1[3], 0.f));
        if (!valid) { p0 = 0u; p1 = 0u; p2 = 0u; p3 = 0u; }
        return make_uint4(p0, p1, p2, p3);
    };
    auto wr_tile = [&](int mt, uint4 v) {
        *(uint4*)(smem + wo + mt * 1152) = v;
    };

    // phase A: tiles 0..34 (write region disjoint from planes)
#pragma unroll 5
    for (int it = 0; it < 5; ++it) {
        int mt = w + it * 8;
        if (mt <= 34) {
            uint4 v = do_tile(mt);
            wr_tile(mt, v);
        }
    }
    // phase B: tiles 35..38 held by waves 0..3 (bytes overlap planes)
    {
        bool hold = (w < 4);
        uint4 hA = make_uint4(0u, 0u, 0u, 0u);
        int mt0 = 35 + w;
        if (hold) hA = do_tile(mt0);
        __syncthreads();                 // planes dead from here
        if (hold) wr_tile(mt0, hA);
    }
    __syncthreads();

    // ---------------- conv2: M=512(pad), N=32, K=288, tap-outer ----------------
    // read(tap ky,kx) = smem + (kx==1 ? bO : bE)[tt] + 3744*ky + (kx==2?144:0)
    f4v acc[4][2];
#pragma unroll
    for (int i = 0; i < 4; ++i) { acc[i][0] = cb0; acc[i][1] = cb1; }
    int bE[4], bO[4];
#pragma unroll
    for (int tt = 0; tt < 4; ++tt) {
        int m2 = (w * 4 + tt) * 16 + l15;
        unsigned orr = ((unsigned)(m2 * 1311)) >> 16;   // m2/50
        int pu = (m2 + 2 * (int)orr) >> 1;
        pu = (pu > 258) ? 258 : pu;
        bE[tt] = pu * ROWB + (par << 6) + (q << 4);
        bO[tt] = bE[tt] + (par ? 80 : 64);
    }
    __builtin_amdgcn_s_setprio(1);
#pragma unroll
    for (int tp = 0; tp < 9; ++tp) {
        const int ky = tp / 3, kx = tp % 3;
        const int off = 3744 * ky + (kx == 2 ? ROWB : 0);
        s8v b0 = *(const s8v*)&w2p[((tp * 2 + 0) * 64 + lane) * 8];
        s8v b1f = *(const s8v*)&w2p[((tp * 2 + 1) * 64 + lane) * 8];
#pragma unroll
        for (int tt = 0; tt < 4; ++tt) {
            s8v a = *(const s8v*)(smem + (kx == 1 ? bO[tt] : bE[tt]) + off);
            acc[tt][0] = __builtin_amdgcn_mfma_f32_16x16x32_bf16(a, b0, acc[tt][0], 0, 0, 0);
            acc[tt][1] = __builtin_amdgcn_mfma_f32_16x16x32_bf16(a, b1f, acc[tt][1], 0, 0, 0);
        }
    }
    __builtin_amdgcn_s_setprio(0);

    // fused relu + spatial partial sum (bias already in C-in; only tile 31
    // has rows >= 500)
    float ps0 = 0.f, ps1 = 0.f;
#pragma unroll
    for (int tt = 0; tt < 4; ++tt) {
        int tile = w * 4 + tt;             // wave-uniform
        if (tile != 31) {
#pragma unroll
            for (int r = 0; r < 4; ++r) {
                ps0 += fmaxf(acc[tt][0][r], 0.f);
                ps1 += fmaxf(acc[tt][1][r], 0.f);
            }
        } else {
            int mbase = tile * 16 + q * 4;
#pragma unroll
            for (int r = 0; r < 4; ++r) {
                if (mbase + r < 500) {
                    ps0 += fmaxf(acc[tt][0][r], 0.f);
                    ps1 += fmaxf(acc[tt][1][r], 0.f);
                }
            }
        }
    }
    ps0 += __shfl_xor(ps0, 16); ps0 += __shfl_xor(ps0, 32);
    ps1 += __shfl_xor(ps1, 16); ps1 += __shfl_xor(ps1, 32);
    __syncthreads();                       // conv2 reads done -> redbuf alias safe
    if (lane < 16) {
        redbuf[w * 32 + l15] = ps0;
        redbuf[w * 32 + 16 + l15] = ps1;
    }
    __syncthreads();
    if (t < 32) {
        float v = 0.f;
#pragma unroll
        for (int k = 0; k < 8; ++k) v += redbuf[k * 32 + t];
        part[(s * NSTRIP + strip) * 32 + t] = v;
    }
}

// =====================================================================
// per-sample encoder MLP: pooled -> relu(feat@We1) -> r_i
// =====================================================================
__global__ void k_enc(const float* __restrict__ part, const float* __restrict__ xc,
                      const float* __restrict__ We1, const float* __restrict__ be1,
                      const float* __restrict__ We2, const float* __restrict__ be2,
                      float* __restrict__ r_i)
{
    __shared__ float feat[33];
    __shared__ float h[128];
    int s = blockIdx.x, j = threadIdx.x;
    if (j < 32) {
        float v = 0.f;
#pragma unroll
        for (int st = 0; st < NSTRIP; ++st) v += part[(s * NSTRIP + st) * 32 + j];
        feat[j] = v * (1.f / 2500.f);
    }
    if (j == 0) feat[32] = xc[s];
    __syncthreads();
    float a = be1[j];
#pragma unroll 4
    for (int k = 0; k < 33; ++k) a = fmaf(feat[k], We1[k * 128 + j], a);
    h[j] = fmaxf(a, 0.f);
    __syncthreads();
    float r = be2[j];
#pragma unroll 8
    for (int k = 0; k < 128; ++k) r = fmaf(h[k], We2[k * 128 + j], r);
    r_i[s * 128 + j] = r;
}

// =====================================================================
// aggregate r over context, mu/sigma encoder, z = mu + sigma*eps (256 thr)
// =====================================================================
__global__ void k_ms(const float* __restrict__ r_i,
                     const float* __restrict__ Wh, const float* __restrict__ bh,
                     const float* __restrict__ Wmu, const float* __restrict__ bmu,
                     const float* __restrict__ Wsig, const float* __restrict__ bsig,
                     const float* __restrict__ eps, float* __restrict__ out,
                     float* __restrict__ zbuf)
{
    __shared__ float r[128], hr[128], tmp[2][128];
    int b = blockIdx.x, t = threadIdx.x;
    int j = t & 127, g = t >> 7;
    float acc = 0.f;
#pragma unroll 4
    for (int i = g; i < NCTX; i += 2) acc += r_i[(b * NCTX + i) * 128 + j];
    tmp[g][j] = acc;
    __syncthreads();
    if (g == 0) r[j] = (tmp[0][j] + tmp[1][j]) * (1.f / 64.f);
    __syncthreads();
    float a = (g == 0) ? bh[j] : 0.f;
#pragma unroll 8
    for (int k = g * 64; k < g * 64 + 64; ++k) a = fmaf(r[k], Wh[k * 128 + j], a);
    tmp[g][j] = a;
    __syncthreads();
    if (g == 0) hr[j] = fmaxf(tmp[0][j] + tmp[1][j], 0.f);
    __syncthreads();
    if (j < 64) {
        float m = (g == 0) ? bmu[j] : 0.f, sg = (g == 0) ? bsig[j] : 0.f;
#pragma unroll 8
        for (int k = g * 64; k < g * 64 + 64; ++k) {
            m  = fmaf(hr[k], Wmu[k * 64 + j], m);
            sg = fmaf(hr[k], Wsig[k * 64 + j], sg);
        }
        tmp[g][j] = m; tmp[g][64 + j] = sg;
    }
    __syncthreads();
    if (t < 64) {
        float m  = tmp[0][t] + tmp[1][t];
        float sg = tmp[0][64 + t] + tmp[1][64 + t];
        float sig = 0.1f + 0.9f / (1.f + expf(-sg));
        out[10240000 + b * 64 + t] = m;      // mu_c
        out[10241024 + b * 64 + t] = sig;    // sigma_c
        zbuf[b * 64 + t] = m + sig * eps[b * 64 + t];
    }
}

// =====================================================================
// decoder hidden: 512 blocks x 256 thr, 4 rows/block (2 per half-group)
// =====================================================================
__global__ __launch_bounds__(256) void k_dec1(
    const float* __restrict__ xt, const float* __restrict__ zbuf,
    const float* __restrict__ Wd1, const float* __restrict__ bd1,
    const float* __restrict__ Wd2, const float* __restrict__ bd2,
    unsigned short* __restrict__ h2d)
{
    __shared__ float zsh[64];
    __shared__ float vsh[2][128];
    __shared__ float h1sh[4][128];
    int t = threadIdx.x;
    int j = t & 127, g = t >> 7;
    int r0 = blockIdx.x * 4;
    int b = r0 >> 7;
    if (t < 64) zsh[t] = zbuf[b * 64 + t];
    __syncthreads();
    float v = (g == 0) ? bd1[j] : 0.f;
#pragma unroll 8
    for (int k = g * 32; k < g * 32 + 32; ++k)
        v = fmaf(zsh[k], Wd1[(1 + k) * 128 + j], v);
    vsh[g][j] = v;
    __syncthreads();
    float vv = vsh[0][j] + vsh[1][j];
    float w0 = Wd1[j];
    int ra = r0 + g * 2;
    float x0 = xt[ra], x1 = xt[ra + 1];
    h1sh[g * 2][j]     = fmaxf(fmaf(x0, w0, vv), 0.f);
    h1sh[g * 2 + 1][j] = fmaxf(fmaf(x1, w0, vv), 0.f);
    __syncthreads();
    float bd2j = bd2[j];
    float a0 = bd2j, a1 = bd2j;
#pragma unroll 8
    for (int k = 0; k < 128; ++k) {
        float wv = Wd2[k * 128 + j];
        a0 = fmaf(h1sh[g * 2][k], wv, a0);
        a1 = fmaf(h1sh[g * 2 + 1][k], wv, a1);
    }
    h2d[(size_t)ra * 128 + j]       = f2bf(fmaxf(a0, 0.f));
    h2d[(size_t)(ra + 1) * 128 + j] = f2bf(fmaxf(a1, 0.f));
}

// =====================================================================
// big decoder GEMM: [2048,128] @ [128,2500], BOTH heads per block,
// bias preloaded into accumulator C-in
// =====================================================================
__global__ __launch_bounds__(256) void k_gemm(
    const unsigned short* __restrict__ h2d, const unsigned short* __restrict__ wdp,
    const float* __restrict__ bdmu, const float* __restrict__ bdsg,
    float* __restrict__ out)
{
    __shared__ __align__(16) unsigned short Al[64 * 128];
    int t = threadIdx.x, lane = t & 63, w = t >> 6;
    int m0 = blockIdx.x * 64;
#pragma unroll
    for (int i = 0; i < 4; ++i) {
        int g = t + i * 256;
        int row = g >> 4, bk = g & 15;
        uint4 v = *(const uint4*)&h2d[(size_t)(m0 + row) * 128 + bk * 8];
        *(uint4*)&Al[row * 128 + ((bk ^ (row & 7)) << 3)] = v;
    }
    __syncthreads();
    int nt = blockIdx.y * 4 + w;
    if (nt < 157) {
        int lcol = lane & 15, lq = lane >> 4;
        int col = nt * 16 + lcol;
        bool cok = (col < 2500);
#pragma unroll
        for (int which = 0; which < 2; ++which) {
            const unsigned short* wp = wdp + (size_t)which * (157 * 4 * 64 * 8);
            s8v bfr[4];
#pragma unroll
            for (int ks = 0; ks < 4; ++ks)
                bfr[ks] = *(const s8v*)&wp[((nt * 4 + ks) * 64 + lane) * 8];
            float bv = cok ? (which ? bdsg[col] : bdmu[col]) : 0.f;
            f4v acc[4];
            {
                f4v bcast = {bv, bv, bv, bv};
#pragma unroll
                for (int mt = 0; mt < 4; ++mt) acc[mt] = bcast;
            }
#pragma unroll
            for (int mt = 0; mt < 4; ++mt) {
                int mrow = mt * 16 + lcol;
#pragma unroll
                for (int ks = 0; ks < 4; ++ks) {
                    int bk = ks * 4 + lq;
                    s8v a = *(const s8v*)&Al[mrow * 128 + ((bk ^ (mrow & 7)) << 3)];
                    acc[mt] = __builtin_amdgcn_mfma_f32_16x16x32_bf16(a, bfr[ks], acc[mt], 0, 0, 0);
                }
            }
            if (cok) {
                size_t zoff = (size_t)which * 5120000;
#pragma unroll
                for (int mt = 0; mt < 4; ++mt)
#pragma unroll
                    for (int r = 0; r < 4; ++r) {
                        int row = m0 + mt * 16 + lq * 4 + r;
                        float vv = acc[mt][r];
                        if (which) {
                            float sp = fmaxf(vv, 0.f) + log1pf(expf(-fabsf(vv)));
                            vv = 0.1f + 0.9f * sp;
                        }
                        out[zoff + (size_t)row * 2500 + col] = vv;
                    }
            }
        }
    }
}

// =====================================================================
extern "C" void kernel_launch(void* const* d_in, const int* in_sizes, int n_in,
                              void* d_out, int out_size, void* d_ws, size_t ws_size,
                              hipStream_t stream)
{
    const float* xc   = (const float*)d_in[0];
    const float* yc   = (const float*)d_in[1];
    const float* xt   = (const float*)d_in[2];
    const float* eps  = (const float*)d_in[3];
    const float* w1   = (const float*)d_in[4];
    const float* b1   = (const float*)d_in[5];
    const float* w2   = (const float*)d_in[6];
    const float* b2   = (const float*)d_in[7];
    const float* We1  = (const float*)d_in[8];
    const float* be1  = (const float*)d_in[9];
    const float* We2  = (const float*)d_in[10];
    const float* be2  = (const float*)d_in[11];
    const float* Wh   = (const float*)d_in[12];
    const float* bh   = (const float*)d_in[13];
    const float* Wmu  = (const float*)d_in[14];
    const float* bmu  = (const float*)d_in[15];
    const float* Wsig = (const float*)d_in[16];
    const float* bsig = (const float*)d_in[17];
    const float* Wd1  = (const float*)d_in[18];
    const float* bd1  = (const float*)d_in[19];
    const float* Wd2  = (const float*)d_in[20];
    const float* bd2  = (const float*)d_in[21];
    const float* Wdmu = (const float*)d_in[22];
    const float* bdmu = (const float*)d_in[23];
    const float* Wdsg = (const float*)d_in[24];
    const float* bdsg = (const float*)d_in[25];

    float* out = (float*)d_out;
    char* wsb  = (char*)d_ws;
    unsigned short* w2p = (unsigned short*)(wsb + 0);
    unsigned short* wdp = (unsigned short*)(wsb + 18432);
    float* part = (float*)(wsb + 1304576);
    float* r_i  = (float*)(wsb + 1959936);
    float* zbuf = (float*)(wsb + 2484224);
    unsigned short* h2d = (unsigned short*)(wsb + 2488320);
    unsigned short* w1p = (unsigned short*)(wsb + 3012608);
    float* treg = (float*)(wsb + 3014656);

    hipLaunchKernelGGL(k_pack, dim3(157, 3), dim3(256), 0, stream,
                       w1, b1, w2, w2p, w1p, treg, Wdmu, Wdsg, wdp);
    hipLaunchKernelGGL(k_conv, dim3(BN * NSTRIP), dim3(512), 0, stream,
                       xc, yc, w1p, w2p, b1, b2, treg, part);
    hipLaunchKernelGGL(k_enc, dim3(BN), dim3(128), 0, stream,
                       part, xc, We1, be1, We2, be2, r_i);
    hipLaunchKernelGGL(k_ms, dim3(BATCH), dim3(256), 0, stream,
                       r_i, Wh, bh, Wmu, bmu, Wsig, bsig, eps, out, zbuf);
    hipLaunchKernelGGL(k_dec1, dim3(512), dim3(256), 0, stream,
                       xt, zbuf, Wd1, bd1, Wd2, bd2, h2d);
    hipLaunchKernelGGL(k_gemm, dim3(32, 40), dim3(256), 0, stream,
                       h2d, wdp, bdmu, bdsg, out);
}